// Round 5
// baseline (297.938 us; speedup 1.0000x reference)
//
#include <hip/hip_runtime.h>
#include <stdint.h>

#define B_SZ 8192
#define N_F 12
#define H_DIM 512
#define K_DIM 1024
#define V_DIM 256

typedef __attribute__((ext_vector_type(8))) __bf16 bf16x8;
typedef __attribute__((ext_vector_type(4))) float f32x4;

// tanh-approx GELU in sigmoid form; |err| vs exact erf-GELU ~1e-3 << 4.6e-2.
__device__ inline float gelu_f(float x) {
  float t = 1.5957691216057308f * x * (1.0f + 0.044715f * x * x);
  return x / (1.0f + __expf(-t));
}

__device__ inline void gld_lds16(const void* g, void* l) {
  __builtin_amdgcn_global_load_lds(
      (const __attribute__((address_space(1))) void*)g,
      (__attribute__((address_space(3))) void*)l, 16, 0, 0);
}

// ---------------------------------------------------------------------------
// Kernel 1 (R2-verified form): wave-per-row, emits FULL K=1024 activation
// row per n. act2 [N][B][K] bf16, 16B-chunk XOR swizzle within each 64-elem
// K-group (chunk c at slot c^(b&7)) so k_gemm's contiguous global_load_lds
// staging lands conflict-free in LDS.
// ---------------------------------------------------------------------------
__global__ __launch_bounds__(256, 4) void k_prep(
    const float* __restrict__ ie, const int* __restrict__ feat,
    const float* __restrict__ tab, const float* __restrict__ gam,
    const float* __restrict__ bet, __bf16* __restrict__ act2) {
  const int lane = threadIdx.x & 63;
  const int b = blockIdx.x * 4 + (threadIdx.x >> 6);

  const float* cb = ie + (size_t)b * H_DIM + lane * 8;
  float4 c0 = *(const float4*)cb;
  float4 c1 = *(const float4*)(cb + 4);
  float s = c0.x + c0.y + c0.z + c0.w + c1.x + c1.y + c1.z + c1.w;
  float q = c0.x * c0.x + c0.y * c0.y + c0.z * c0.z + c0.w * c0.w +
            c1.x * c1.x + c1.y * c1.y + c1.z * c1.z + c1.w * c1.w;
#pragma unroll
  for (int o = 1; o < 64; o <<= 1) {
    s += __shfl_xor(s, o, 64);
    q += __shfl_xor(q, o, 64);
  }
  const float S1 = s, Q1 = q;

  const float4 gl0 = *(const float4*)(gam + lane * 8);
  const float4 gl1 = *(const float4*)(gam + lane * 8 + 4);
  const float4 el0 = *(const float4*)(bet + lane * 8);
  const float4 el1 = *(const float4*)(bet + lane * 8 + 4);
  const float4 g0 = *(const float4*)(gam + H_DIM + lane * 8);
  const float4 g1 = *(const float4*)(gam + H_DIM + lane * 8 + 4);
  const float4 e0 = *(const float4*)(bet + H_DIM + lane * 8);
  const float4 e1 = *(const float4*)(bet + H_DIM + lane * 8 + 4);

  float r[8];
#pragma unroll
  for (int i = 0; i < 8; ++i) r[i] = 0.f;

  const int sw = (lane & ~7) | ((lane & 7) ^ (b & 7));
  __bf16* arow = act2 + (size_t)b * K_DIM + sw * 8;

  for (int n = 0; n < N_F; ++n) {
    s = 0.f; q = 0.f;
#pragma unroll
    for (int i = 0; i < 8; ++i) { s += r[i]; q += r[i] * r[i]; }
#pragma unroll
    for (int o = 1; o < 64; o <<= 1) {
      s += __shfl_xor(s, o, 64);
      q += __shfl_xor(q, o, 64);
    }
    const float mean = (S1 + s) * (1.0f / 1024.0f);
    const float var = (Q1 + q) * (1.0f / 1024.0f) - mean * mean;
    const float rs = rsqrtf(var + 1e-5f);

    // issue next gather early so latency hides under the gelu work
    float4 t0, t1;
    const bool have = (n < N_F - 1);
    if (have) {
      const int f = feat[b * N_F + n];
      const float* tr = tab + ((size_t)n * V_DIM + f) * H_DIM + lane * 8;
      t0 = *(const float4*)tr;
      t1 = *(const float4*)(tr + 4);
    }

    // ctx half (k in [0,512))
    bf16x8 pc;
    pc[0] = (__bf16)gelu_f((c0.x - mean) * rs * gl0.x + el0.x);
    pc[1] = (__bf16)gelu_f((c0.y - mean) * rs * gl0.y + el0.y);
    pc[2] = (__bf16)gelu_f((c0.z - mean) * rs * gl0.z + el0.z);
    pc[3] = (__bf16)gelu_f((c0.w - mean) * rs * gl0.w + el0.w);
    pc[4] = (__bf16)gelu_f((c1.x - mean) * rs * gl1.x + el1.x);
    pc[5] = (__bf16)gelu_f((c1.y - mean) * rs * gl1.y + el1.y);
    pc[6] = (__bf16)gelu_f((c1.z - mean) * rs * gl1.z + el1.z);
    pc[7] = (__bf16)gelu_f((c1.w - mean) * rs * gl1.w + el1.w);
    *(bf16x8*)(arow + (size_t)n * B_SZ * K_DIM) = pc;

    // masked-sums half (k in [512,1024))
    bf16x8 pk;
    pk[0] = (__bf16)gelu_f((r[0] - mean) * rs * g0.x + e0.x);
    pk[1] = (__bf16)gelu_f((r[1] - mean) * rs * g0.y + e0.y);
    pk[2] = (__bf16)gelu_f((r[2] - mean) * rs * g0.z + e0.z);
    pk[3] = (__bf16)gelu_f((r[3] - mean) * rs * g0.w + e0.w);
    pk[4] = (__bf16)gelu_f((r[4] - mean) * rs * g1.x + e1.x);
    pk[5] = (__bf16)gelu_f((r[5] - mean) * rs * g1.y + e1.y);
    pk[6] = (__bf16)gelu_f((r[6] - mean) * rs * g1.z + e1.z);
    pk[7] = (__bf16)gelu_f((r[7] - mean) * rs * g1.w + e1.w);
    *(bf16x8*)(arow + (size_t)n * B_SZ * K_DIM + H_DIM) = pk;

    if (have) {
      r[0] += t0.x; r[1] += t0.y; r[2] += t0.z; r[3] += t0.w;
      r[4] += t1.x; r[5] += t1.y; r[6] += t1.z; r[7] += t1.w;
    }
  }
}

// ---------------------------------------------------------------------------
// Kernel 2: pred_W [N][K][V] fp32 -> Wt [N][V][K] bf16, chunk-swizzled by v&7
// so that gld staging in k_gemm lands conflict-free in LDS.
// ---------------------------------------------------------------------------
__global__ __launch_bounds__(256) void k_wt(const float* __restrict__ W,
                                            __bf16* __restrict__ Wt) {
  __shared__ float tile[32][33];
  const int bid = blockIdx.x;
  const int n = bid >> 8;
  const int rem = bid & 255;
  const int kt = rem >> 3, vt = rem & 7;
  const int tx = threadIdx.x & 31, ty = threadIdx.x >> 5;
  const float* src = W + (size_t)n * K_DIM * V_DIM;
#pragma unroll
  for (int i = 0; i < 4; ++i) {
    const int k = kt * 32 + ty + i * 8;
    tile[ty + i * 8][tx] = src[(size_t)k * V_DIM + vt * 32 + tx];
  }
  __syncthreads();
  __bf16* dst = Wt + (size_t)n * V_DIM * K_DIM;
  const int t = threadIdx.x;
  if (t < 128) {
    const int v_l = t >> 2, c_l = t & 3;
    const int v = vt * 32 + v_l;
    bf16x8 pk;
#pragma unroll
    for (int e = 0; e < 8; ++e) pk[e] = (__bf16)tile[c_l * 8 + e][v_l];
    const int gc = kt * 4 + c_l;
    const int swc = (gc & ~7) | ((gc & 7) ^ (v & 7));
    *(bf16x8*)(dst + (size_t)v * K_DIM + swc * 8) = pk;
  }
}

// ---------------------------------------------------------------------------
// Kernel 3: pure GEMM, phase-split schedule (T3+T4+T5, m196/m201 mechanism).
// grid = (B/128, N), 512 threads (8 waves 2x4). BM=128 BN=256 BK=64.
// Depth-3 LDS buffers (144 KB, 1 block/CU). Per K-step: 2 phases, each
// {ds_read fragments || issue 3 glds of tile kt+2 -> barrier -> setprio(1)
// 16 MFMA setprio(0) -> barrier}; counted vmcnt(6) ONCE per K-step (end of
// phase B) so tile kt+2's 6 loads stay in flight across the boundary.
// Race ledger: stage target buf[(kt+2)%3]=buf[(kt-1)%3]; its readers'
// ds_reads completed before their MFMAs (compiler lgkm) which precede step
// kt-1's final barrier. In-order vmcnt: <=12 in flight at step end; wait to
// 6 => tile kt+1 landed. Tail: step 14 issues nothing -> vmcnt(0).
// ---------------------------------------------------------------------------
__global__ __launch_bounds__(512, 2) void k_gemm(
    const __bf16* __restrict__ act2, const __bf16* __restrict__ Wt,
    const float* __restrict__ bias, float* __restrict__ out) {
  constexpr int BM = 128, BN = 256, BK = 64;
  __shared__ __align__(16) __bf16 As[3][BM * BK];  // 3 x 16 KB
  __shared__ __align__(16) __bf16 Ws[3][BN * BK];  // 3 x 32 KB (144 KB total)

  const int n = blockIdx.y;
  const int b0 = blockIdx.x * BM;
  const int t = threadIdx.x;
  const int lane = t & 63;
  const int w = t >> 6;
  const int wm = w & 1;
  const int wn = w >> 1;
  const int l15 = lane & 15;
  const int lq = lane >> 4;
  const int lr8 = lane >> 3;
  const int lo8 = lane & 7;

  const __bf16* act2n = act2 + (size_t)n * B_SZ * K_DIM;
  const __bf16* Wtn = Wt + (size_t)n * V_DIM * K_DIM;

  f32x4 acc[4][4];
#pragma unroll
  for (int i = 0; i < 4; ++i)
#pragma unroll
    for (int j = 0; j < 4; ++j) acc[i][j] = (f32x4){0.f, 0.f, 0.f, 0.f};

  // --- staging helpers: 6 gld_lds16 per wave per tile (4 W + 2 A) ---
  auto stageW3 = [&](int buf, int kt) {  // first 3 W-loads
    const int k0 = kt * BK;
#pragma unroll
    for (int p = 0; p < 3; ++p) {
      const int v0 = w * 32 + p * 8;
      gld_lds16(Wtn + (size_t)(v0 + lr8) * K_DIM + k0 + lo8 * 8,
                &Ws[buf][v0 * BK]);
    }
  };
  auto stageRest = [&](int buf, int kt) {  // last W-load + 2 A-loads
    const int k0 = kt * BK;
    {
      const int v0 = w * 32 + 3 * 8;
      gld_lds16(Wtn + (size_t)(v0 + lr8) * K_DIM + k0 + lo8 * 8,
                &Ws[buf][v0 * BK]);
    }
#pragma unroll
    for (int p = 0; p < 2; ++p) {
      const int r0 = w * 16 + p * 8;
      gld_lds16(act2n + (size_t)(b0 + r0 + lr8) * K_DIM + k0 + lo8 * 8,
                &As[buf][r0 * BK]);
    }
  };

  // --- prologue: tiles 0 and 1 in flight; wait for tile 0 only ---
  stageW3(0, 0); stageRest(0, 0);
  stageW3(1, 1); stageRest(1, 1);
  asm volatile("s_waitcnt vmcnt(6)" ::: "memory");
  asm volatile("s_barrier" ::: "memory");

#pragma unroll
  for (int kt = 0; kt < 16; ++kt) {
    const int cur = kt % 3;
    const int nxt = (kt + 2) % 3;
#pragma unroll
    for (int ks = 0; ks < 2; ++ks) {
      // --- fragment ds_reads for this half K-step ---
      const int cs = ks * 4 + lq;
      bf16x8 af[4], bb[4];
#pragma unroll
      for (int i = 0; i < 4; ++i) {
        const int row = wm * 64 + i * 16 + l15;
        af[i] = *(const bf16x8*)(&As[cur][row * BK + ((cs ^ (row & 7)) << 3)]);
      }
#pragma unroll
      for (int j = 0; j < 4; ++j) {
        const int row = wn * 64 + j * 16 + l15;
        bb[j] = *(const bf16x8*)(&Ws[cur][row * BK + ((cs ^ (row & 7)) << 3)]);
      }
      // --- interleaved staging issue for tile kt+2 ---
      if (kt < 14) {
        if (ks == 0) stageW3(nxt, kt + 2);
        else stageRest(nxt, kt + 2);
      }
      asm volatile("s_barrier" ::: "memory");
      // --- MFMA cluster ---
      __builtin_amdgcn_s_setprio(1);
#pragma unroll
      for (int i = 0; i < 4; ++i)
#pragma unroll
        for (int j = 0; j < 4; ++j)
          acc[i][j] = __builtin_amdgcn_mfma_f32_16x16x32_bf16(af[i], bb[j],
                                                              acc[i][j], 0, 0, 0);
      __builtin_amdgcn_s_setprio(0);
      // --- counted waits: only at end of phase B, never 0 mid-loop ---
      if (ks == 1) {
        if (kt < 14) {
          asm volatile("s_waitcnt vmcnt(6)" ::: "memory");
        } else if (kt == 14) {
          asm volatile("s_waitcnt vmcnt(0)" ::: "memory");
        }
      }
      asm volatile("s_barrier" ::: "memory");
    }
  }

  // epilogue: C/D layout col=lane&15, row=(lane>>4)*4+reg
#pragma unroll
  for (int j = 0; j < 4; ++j) {
    const int v = wn * 64 + j * 16 + l15;
    const float bv = bias[n * V_DIM + v];
#pragma unroll
    for (int i = 0; i < 4; ++i) {
      const int rb = wm * 64 + i * 16 + lq * 4;
#pragma unroll
      for (int r = 0; r < 4; ++r) {
        out[((size_t)(b0 + rb + r) * N_F + n) * V_DIM + v] = acc[i][j][r] + bv;
      }
    }
  }
}

// ---------------------------------------------------------------------------
extern "C" void kernel_launch(void* const* d_in, const int* in_sizes, int n_in,
                              void* d_out, int out_size, void* d_ws, size_t ws_size,
                              hipStream_t stream) {
  const float* ie = (const float*)d_in[0];
  const int* feat = (const int*)d_in[1];
  const float* tab = (const float*)d_in[2];
  const float* gam = (const float*)d_in[3];
  const float* bet = (const float*)d_in[4];
  const float* predW = (const float*)d_in[5];
  const float* predb = (const float*)d_in[6];
  float* out = (float*)d_out;

  char* ws = (char*)d_ws;
  __bf16* act2 = (__bf16*)ws;                        // 201,326,592 B
  __bf16* Wt = (__bf16*)(ws + 201326592);            //   6,291,456 B

  hipLaunchKernelGGL(k_prep, dim3(B_SZ / 4), dim3(256), 0, stream, ie, feat,
                     tab, gam, bet, act2);
  hipLaunchKernelGGL(k_wt, dim3(3072), dim3(256), 0, stream, predW, Wt);
  hipLaunchKernelGGL(k_gemm, dim3(B_SZ / 128, N_F), dim3(512), 0, stream,
                     act2, Wt, predb, out);
}

// Round 6
// 272.953 us; speedup vs baseline: 1.0915x; 1.0915x over previous
//
#include <hip/hip_runtime.h>
#include <stdint.h>

#define B_SZ 8192
#define N_F 12
#define H_DIM 512
#define K_DIM 1024
#define V_DIM 256

typedef __attribute__((ext_vector_type(8))) __bf16 bf16x8;
typedef __attribute__((ext_vector_type(4))) float f32x4;

// tanh-approx GELU in sigmoid form; |err| vs exact erf-GELU ~1e-3 << 4.6e-2.
__device__ inline float gelu_f(float x) {
  float t = 1.5957691216057308f * x * (1.0f + 0.044715f * x * x);
  return x / (1.0f + __expf(-t));
}

__device__ inline void gld_lds16(const void* g, void* l) {
  __builtin_amdgcn_global_load_lds(
      (const __attribute__((address_space(1))) void*)g,
      (__attribute__((address_space(3))) void*)l, 16, 0, 0);
}

// ---------------------------------------------------------------------------
// Kernel 1: wave-per-row, masked-sums half only. Lane l owns dims
// [l*8, l*8+8). Activation stored INTO d_out (aliased scratch): layout
// [B][N][H=512] bf16 — cell (b,n) occupies the same 1KB slot as
// out[b][n][0..255] fp32, read and later overwritten by the same k_gemm
// block. 16B-chunk XOR swizzle (chunk c at slot c^(b&7)).
// stats[b][n] = (mean, rsqrt).
// ---------------------------------------------------------------------------
__global__ __launch_bounds__(256, 8) void k_prep(
    const float* __restrict__ ie, const int* __restrict__ feat,
    const float* __restrict__ tab, const float* __restrict__ gam,
    const float* __restrict__ bet, __bf16* actA,
    float* __restrict__ stats) {
  const int lane = threadIdx.x & 63;
  const int b = blockIdx.x * 4 + (threadIdx.x >> 6);

  const float* cb = ie + (size_t)b * H_DIM + lane * 8;
  float4 c0 = *(const float4*)cb;
  float4 c1 = *(const float4*)(cb + 4);
  float s = c0.x + c0.y + c0.z + c0.w + c1.x + c1.y + c1.z + c1.w;
  float q = c0.x * c0.x + c0.y * c0.y + c0.z * c0.z + c0.w * c0.w +
            c1.x * c1.x + c1.y * c1.y + c1.z * c1.z + c1.w * c1.w;
#pragma unroll
  for (int o = 1; o < 64; o <<= 1) {
    s += __shfl_xor(s, o, 64);
    q += __shfl_xor(q, o, 64);
  }
  const float S1 = s, Q1 = q;

  const float4 g0 = *(const float4*)(gam + H_DIM + lane * 8);
  const float4 g1 = *(const float4*)(gam + H_DIM + lane * 8 + 4);
  const float4 e0 = *(const float4*)(bet + H_DIM + lane * 8);
  const float4 e1 = *(const float4*)(bet + H_DIM + lane * 8 + 4);

  float r[8];
#pragma unroll
  for (int i = 0; i < 8; ++i) r[i] = 0.f;

  const int sw = (lane & ~7) | ((lane & 7) ^ (b & 7));
  __bf16* arow = actA + (size_t)b * N_F * H_DIM + sw * 8;

  for (int n = 0; n < N_F; ++n) {
    s = 0.f; q = 0.f;
#pragma unroll
    for (int i = 0; i < 8; ++i) { s += r[i]; q += r[i] * r[i]; }
#pragma unroll
    for (int o = 1; o < 64; o <<= 1) {
      s += __shfl_xor(s, o, 64);
      q += __shfl_xor(q, o, 64);
    }
    const float mean = (S1 + s) * (1.0f / 1024.0f);
    const float var = (Q1 + q) * (1.0f / 1024.0f) - mean * mean;
    const float rs = rsqrtf(var + 1e-5f);
    if (lane == 0)
      *(float2*)(stats + ((size_t)b * N_F + n) * 2) = make_float2(mean, rs);

    // issue next gather early so latency hides under the gelu work
    float4 t0, t1;
    const bool have = (n < N_F - 1);
    if (have) {
      const int f = feat[b * N_F + n];
      const float* tr = tab + ((size_t)n * V_DIM + f) * H_DIM + lane * 8;
      t0 = *(const float4*)tr;
      t1 = *(const float4*)(tr + 4);
    }

    bf16x8 pk;
    pk[0] = (__bf16)gelu_f((r[0] - mean) * rs * g0.x + e0.x);
    pk[1] = (__bf16)gelu_f((r[1] - mean) * rs * g0.y + e0.y);
    pk[2] = (__bf16)gelu_f((r[2] - mean) * rs * g0.z + e0.z);
    pk[3] = (__bf16)gelu_f((r[3] - mean) * rs * g0.w + e0.w);
    pk[4] = (__bf16)gelu_f((r[4] - mean) * rs * g1.x + e1.x);
    pk[5] = (__bf16)gelu_f((r[5] - mean) * rs * g1.y + e1.y);
    pk[6] = (__bf16)gelu_f((r[6] - mean) * rs * g1.z + e1.z);
    pk[7] = (__bf16)gelu_f((r[7] - mean) * rs * g1.w + e1.w);
    *(bf16x8*)(arow + (size_t)n * H_DIM) = pk;

    if (have) {
      r[0] += t0.x; r[1] += t0.y; r[2] += t0.z; r[3] += t0.w;
      r[4] += t1.x; r[5] += t1.y; r[6] += t1.z; r[7] += t1.w;
    }
  }
}

// ---------------------------------------------------------------------------
// Kernel 2: pred_W [N][K][V] fp32 -> Wt [N][V][K] bf16, chunk-swizzled by v&7
// so that gld staging in k_gemm lands conflict-free in LDS.
// ---------------------------------------------------------------------------
__global__ __launch_bounds__(256) void k_wt(const float* __restrict__ W,
                                            __bf16* __restrict__ Wt) {
  __shared__ float tile[32][33];
  const int bid = blockIdx.x;
  const int n = bid >> 8;
  const int rem = bid & 255;
  const int kt = rem >> 3, vt = rem & 7;
  const int tx = threadIdx.x & 31, ty = threadIdx.x >> 5;
  const float* src = W + (size_t)n * K_DIM * V_DIM;
#pragma unroll
  for (int i = 0; i < 4; ++i) {
    const int k = kt * 32 + ty + i * 8;
    tile[ty + i * 8][tx] = src[(size_t)k * V_DIM + vt * 32 + tx];
  }
  __syncthreads();
  __bf16* dst = Wt + (size_t)n * V_DIM * K_DIM;
  const int t = threadIdx.x;
  if (t < 128) {
    const int v_l = t >> 2, c_l = t & 3;
    const int v = vt * 32 + v_l;
    bf16x8 pk;
#pragma unroll
    for (int e = 0; e < 8; ++e) pk[e] = (__bf16)tile[c_l * 8 + e][v_l];
    const int gc = kt * 4 + c_l;
    const int swc = (gc & ~7) | ((gc & 7) ^ (v & 7));
    *(bf16x8*)(dst + (size_t)v * K_DIM + swc * 8) = pk;
  }
}

// ---------------------------------------------------------------------------
// Kernel 3: GEMM, R2's proven 2-barrier single-buffer loop (48 KB LDS).
// grid = (B/128, N), 512 threads (8 waves 2x4). BM=128 BN=256 BK=64.
// ctx half (kt<8): LN+GELU once in a COALESCED prologue (8 lanes/row:
// each wave covers 8 contiguous 256B row segments), 64 VGPR of ctx frags,
// contributed per K-step via 2 swizzled ds_write_b128 (cheap, no vmcnt).
// masked half (kt>=8): read from actA (= d_out alias) via gld_lds.
// Alias note: actA/out alias by design; block (b0,n) reads act[b][n] in
// K-steps 8..15 and writes out[b][n] only in the epilogue (data+barrier
// ordered). No __restrict__ on the aliased pointers.
// ---------------------------------------------------------------------------
__global__ __launch_bounds__(512, 2) void k_gemm(
    const float* __restrict__ ie, const __bf16* actA,
    const __bf16* __restrict__ Wt, const float* __restrict__ stats,
    const float* __restrict__ gam, const float* __restrict__ bet,
    const float* __restrict__ bias, float* out) {
  constexpr int BM = 128, BN = 256, BK = 64;
  __shared__ __align__(16) __bf16 As[BM * BK];  // 16 KB
  __shared__ __align__(16) __bf16 Ws[BN * BK];  // 32 KB

  const int n = blockIdx.y;
  const int b0 = blockIdx.x * BM;
  const int t = threadIdx.x;
  const int lane = t & 63;
  const int w = t >> 6;
  const int wm = w & 1;
  const int wn = w >> 1;
  const int l15 = lane & 15;
  const int lq = lane >> 4;
  const int lr8 = lane >> 3;
  const int lo8 = lane & 7;

  const __bf16* Wtn = Wt + (size_t)n * V_DIM * K_DIM;

  // ---- prologue: ctx -> regs, LN+GELU once, coalesced loads ----
  // thread t: rows pr+64h (pr=t>>3), chunk pm=t&7 (8 floats at col pm*8
  // of each 64-col K-group). Wave load = 8 rows x 256B contiguous.
  const int pr = t >> 3;
  const int pm = t & 7;
  bf16x8 ctx[16];
  {
#pragma unroll
    for (int h = 0; h < 2; ++h) {
      const int row = b0 + pr + 64 * h;
      const float2 st = *(const float2*)(stats + ((size_t)row * N_F + n) * 2);
      const float mu = st.x, rs = st.y;
      const float* ierow = ie + (size_t)row * H_DIM;
#pragma unroll
      for (int k8 = 0; k8 < 8; ++k8) {
        const int col = k8 * 64 + pm * 8;
        const float4 x0 = *(const float4*)(ierow + col);
        const float4 x1 = *(const float4*)(ierow + col + 4);
        const float4 gg0 = *(const float4*)(gam + col);
        const float4 gg1 = *(const float4*)(gam + col + 4);
        const float4 bb0 = *(const float4*)(bet + col);
        const float4 bb1 = *(const float4*)(bet + col + 4);
        bf16x8 pk;
        pk[0] = (__bf16)gelu_f((x0.x - mu) * rs * gg0.x + bb0.x);
        pk[1] = (__bf16)gelu_f((x0.y - mu) * rs * gg0.y + bb0.y);
        pk[2] = (__bf16)gelu_f((x0.z - mu) * rs * gg0.z + bb0.z);
        pk[3] = (__bf16)gelu_f((x0.w - mu) * rs * gg0.w + bb0.w);
        pk[4] = (__bf16)gelu_f((x1.x - mu) * rs * gg1.x + bb1.x);
        pk[5] = (__bf16)gelu_f((x1.y - mu) * rs * gg1.y + bb1.y);
        pk[6] = (__bf16)gelu_f((x1.z - mu) * rs * gg1.z + bb1.z);
        pk[7] = (__bf16)gelu_f((x1.w - mu) * rs * gg1.w + bb1.w);
        ctx[k8 * 2 + h] = pk;
      }
    }
  }

  // swizzled ds_write slots (row & 7 == pr & 7 for both halves)
  const int swo = (pm ^ (pr & 7)) << 3;

  f32x4 acc[4][4];
#pragma unroll
  for (int i = 0; i < 4; ++i)
#pragma unroll
    for (int j = 0; j < 4; ++j) acc[i][j] = (f32x4){0.f, 0.f, 0.f, 0.f};

#pragma unroll
  for (int kt = 0; kt < 16; ++kt) {
    const int k0 = kt * BK;
    __syncthreads();
    // --- stage W tile (pre-swizzled global -> contiguous gld) ---
#pragma unroll
    for (int p = 0; p < 4; ++p) {
      const int v0 = w * 32 + p * 8;
      gld_lds16(Wtn + (size_t)(v0 + lr8) * K_DIM + k0 + lo8 * 8, Ws + v0 * BK);
    }
    if (kt < 8) {
      // --- A from ctx regs: 2 swizzled ds_writes, no memory wait ---
      *(bf16x8*)(As + (pr)*BK + swo) = ctx[kt * 2 + 0];
      *(bf16x8*)(As + (pr + 64) * BK + swo) = ctx[kt * 2 + 1];
    } else {
      // --- A from actA (= d_out alias, pre-swizzled bf16): async copy ---
#pragma unroll
      for (int p = 0; p < 2; ++p) {
        const int r0 = w * 16 + p * 8;
        gld_lds16(actA + ((size_t)(b0 + r0 + lr8) * N_F + n) * H_DIM +
                      (k0 - H_DIM) + lo8 * 8,
                  As + r0 * BK);
      }
    }
    __syncthreads();
    // --- 2 MFMA k-steps, swizzled fragment reads ---
#pragma unroll
    for (int ks = 0; ks < 2; ++ks) {
      const int cs = ks * 4 + lq;
      bf16x8 af[4], bb[4];
#pragma unroll
      for (int i = 0; i < 4; ++i) {
        const int row = wm * 64 + i * 16 + l15;
        af[i] = *(const bf16x8*)(As + row * BK + ((cs ^ (row & 7)) << 3));
      }
#pragma unroll
      for (int j = 0; j < 4; ++j) {
        const int row = wn * 64 + j * 16 + l15;
        bb[j] = *(const bf16x8*)(Ws + row * BK + ((cs ^ (row & 7)) << 3));
      }
#pragma unroll
      for (int i = 0; i < 4; ++i)
#pragma unroll
        for (int j = 0; j < 4; ++j)
          acc[i][j] = __builtin_amdgcn_mfma_f32_16x16x32_bf16(af[i], bb[j],
                                                              acc[i][j], 0, 0, 0);
    }
  }

  // epilogue: C/D layout col=lane&15, row=(lane>>4)*4+reg
#pragma unroll
  for (int j = 0; j < 4; ++j) {
    const int v = wn * 64 + j * 16 + l15;
    const float bv = bias[n * V_DIM + v];
#pragma unroll
    for (int i = 0; i < 4; ++i) {
      const int rb = wm * 64 + i * 16 + lq * 4;
#pragma unroll
      for (int r = 0; r < 4; ++r) {
        out[((size_t)(b0 + rb + r) * N_F + n) * V_DIM + v] = acc[i][j][r] + bv;
      }
    }
  }
}

// ---------------------------------------------------------------------------
extern "C" void kernel_launch(void* const* d_in, const int* in_sizes, int n_in,
                              void* d_out, int out_size, void* d_ws, size_t ws_size,
                              hipStream_t stream) {
  const float* ie = (const float*)d_in[0];
  const int* feat = (const int*)d_in[1];
  const float* tab = (const float*)d_in[2];
  const float* gam = (const float*)d_in[3];
  const float* bet = (const float*)d_in[4];
  const float* predW = (const float*)d_in[5];
  const float* predb = (const float*)d_in[6];
  float* out = (float*)d_out;

  // activation scratch aliases d_out (exactly out_size bytes)
  __bf16* actA = (__bf16*)d_out;

  char* ws = (char*)d_ws;
  float* stats = (float*)ws;                 //   786,432 B
  __bf16* Wt = (__bf16*)(ws + 786432);       // 6,291,456 B  (ws total ~7 MB)

  hipLaunchKernelGGL(k_prep, dim3(B_SZ / 4), dim3(256), 0, stream, ie, feat,
                     tab, gam, bet, actA, stats);
  hipLaunchKernelGGL(k_wt, dim3(3072), dim3(256), 0, stream, predW, Wt);
  hipLaunchKernelGGL(k_gemm, dim3(B_SZ / 128, N_F), dim3(512), 0, stream, ie,
                     actA, Wt, stats, gam, bet, predb, out);
}

// Round 7
// 269.272 us; speedup vs baseline: 1.1065x; 1.0137x over previous
//
#include <hip/hip_runtime.h>
#include <stdint.h>

#define B_SZ 8192
#define N_F 12
#define H_DIM 512
#define K_DIM 1024
#define V_DIM 256

typedef __attribute__((ext_vector_type(8))) __bf16 bf16x8;
typedef __attribute__((ext_vector_type(4))) float f32x4;

// tanh-approx GELU in sigmoid form; |err| vs exact erf-GELU ~1e-3 << 4.6e-2.
__device__ inline float gelu_f(float x) {
  float t = 1.5957691216057308f * x * (1.0f + 0.044715f * x * x);
  return x / (1.0f + __expf(-t));
}

__device__ inline void gld_lds16(const void* g, void* l) {
  __builtin_amdgcn_global_load_lds(
      (const __attribute__((address_space(1))) void*)g,
      (__attribute__((address_space(3))) void*)l, 16, 0, 0);
}

// ---------------------------------------------------------------------------
// Kernel 1: wave-per-row, masked-sums half only. Lane l owns dims
// [l*8, l*8+8). Activation stored INTO d_out (aliased scratch): layout
// [B][N][H=512] bf16 — cell (b,n) occupies the same 1KB slot as
// out[b][n][0..255] fp32, read and later overwritten by the same k_gemm
// block. 16B-chunk XOR swizzle (chunk c at slot c^(b&7)).
// stats[b][n] = (mean, rsqrt).
// ---------------------------------------------------------------------------
__global__ __launch_bounds__(256, 8) void k_prep(
    const float* __restrict__ ie, const int* __restrict__ feat,
    const float* __restrict__ tab, const float* __restrict__ gam,
    const float* __restrict__ bet, __bf16* actA,
    float* __restrict__ stats) {
  const int lane = threadIdx.x & 63;
  const int b = blockIdx.x * 4 + (threadIdx.x >> 6);

  const float* cb = ie + (size_t)b * H_DIM + lane * 8;
  float4 c0 = *(const float4*)cb;
  float4 c1 = *(const float4*)(cb + 4);
  float s = c0.x + c0.y + c0.z + c0.w + c1.x + c1.y + c1.z + c1.w;
  float q = c0.x * c0.x + c0.y * c0.y + c0.z * c0.z + c0.w * c0.w +
            c1.x * c1.x + c1.y * c1.y + c1.z * c1.z + c1.w * c1.w;
#pragma unroll
  for (int o = 1; o < 64; o <<= 1) {
    s += __shfl_xor(s, o, 64);
    q += __shfl_xor(q, o, 64);
  }
  const float S1 = s, Q1 = q;

  const float4 g0 = *(const float4*)(gam + H_DIM + lane * 8);
  const float4 g1 = *(const float4*)(gam + H_DIM + lane * 8 + 4);
  const float4 e0 = *(const float4*)(bet + H_DIM + lane * 8);
  const float4 e1 = *(const float4*)(bet + H_DIM + lane * 8 + 4);

  float r[8];
#pragma unroll
  for (int i = 0; i < 8; ++i) r[i] = 0.f;

  const int sw = (lane & ~7) | ((lane & 7) ^ (b & 7));
  __bf16* arow = actA + (size_t)b * N_F * H_DIM + sw * 8;

  for (int n = 0; n < N_F; ++n) {
    s = 0.f; q = 0.f;
#pragma unroll
    for (int i = 0; i < 8; ++i) { s += r[i]; q += r[i] * r[i]; }
#pragma unroll
    for (int o = 1; o < 64; o <<= 1) {
      s += __shfl_xor(s, o, 64);
      q += __shfl_xor(q, o, 64);
    }
    const float mean = (S1 + s) * (1.0f / 1024.0f);
    const float var = (Q1 + q) * (1.0f / 1024.0f) - mean * mean;
    const float rs = rsqrtf(var + 1e-5f);
    if (lane == 0)
      *(float2*)(stats + ((size_t)b * N_F + n) * 2) = make_float2(mean, rs);

    // issue next gather early so latency hides under the gelu work
    float4 t0, t1;
    const bool have = (n < N_F - 1);
    if (have) {
      const int f = feat[b * N_F + n];
      const float* tr = tab + ((size_t)n * V_DIM + f) * H_DIM + lane * 8;
      t0 = *(const float4*)tr;
      t1 = *(const float4*)(tr + 4);
    }

    bf16x8 pk;
    pk[0] = (__bf16)gelu_f((r[0] - mean) * rs * g0.x + e0.x);
    pk[1] = (__bf16)gelu_f((r[1] - mean) * rs * g0.y + e0.y);
    pk[2] = (__bf16)gelu_f((r[2] - mean) * rs * g0.z + e0.z);
    pk[3] = (__bf16)gelu_f((r[3] - mean) * rs * g0.w + e0.w);
    pk[4] = (__bf16)gelu_f((r[4] - mean) * rs * g1.x + e1.x);
    pk[5] = (__bf16)gelu_f((r[5] - mean) * rs * g1.y + e1.y);
    pk[6] = (__bf16)gelu_f((r[6] - mean) * rs * g1.z + e1.z);
    pk[7] = (__bf16)gelu_f((r[7] - mean) * rs * g1.w + e1.w);
    *(bf16x8*)(arow + (size_t)n * H_DIM) = pk;

    if (have) {
      r[0] += t0.x; r[1] += t0.y; r[2] += t0.z; r[3] += t0.w;
      r[4] += t1.x; r[5] += t1.y; r[6] += t1.z; r[7] += t1.w;
    }
  }
}

// ---------------------------------------------------------------------------
// Kernel 2: pred_W [N][K][V] fp32 -> Wt [N][V][K] bf16, chunk-swizzled by v&7
// so that gld staging in k_gemm lands conflict-free in LDS.
// ---------------------------------------------------------------------------
__global__ __launch_bounds__(256) void k_wt(const float* __restrict__ W,
                                            __bf16* __restrict__ Wt) {
  __shared__ float tile[32][33];
  const int bid = blockIdx.x;
  const int n = bid >> 8;
  const int rem = bid & 255;
  const int kt = rem >> 3, vt = rem & 7;
  const int tx = threadIdx.x & 31, ty = threadIdx.x >> 5;
  const float* src = W + (size_t)n * K_DIM * V_DIM;
#pragma unroll
  for (int i = 0; i < 4; ++i) {
    const int k = kt * 32 + ty + i * 8;
    tile[ty + i * 8][tx] = src[(size_t)k * V_DIM + vt * 32 + tx];
  }
  __syncthreads();
  __bf16* dst = Wt + (size_t)n * V_DIM * K_DIM;
  const int t = threadIdx.x;
  if (t < 128) {
    const int v_l = t >> 2, c_l = t & 3;
    const int v = vt * 32 + v_l;
    bf16x8 pk;
#pragma unroll
    for (int e = 0; e < 8; ++e) pk[e] = (__bf16)tile[c_l * 8 + e][v_l];
    const int gc = kt * 4 + c_l;
    const int swc = (gc & ~7) | ((gc & 7) ^ (v & 7));
    *(bf16x8*)(dst + (size_t)v * K_DIM + swc * 8) = pk;
  }
}

// ---------------------------------------------------------------------------
// Kernel 3: GEMM, R6's verified 2-barrier loop, K-order permuted (kt^8):
// steps 0..7 consume the MASKED half (pure gld staging) while computing the
// ctx LN+GELU for steps 8..15 in the otherwise-stalled VALU slots; steps
// 8..15 consume ctx from regs via 2 swizzled ds_writes. Accumulation order
// over K is irrelevant; all K remaps are BK=64 swizzle-group-aligned.
// Alias note: actA/out alias by design; block (b0,n) reads act[b][n] in
// K-steps 0..7 and writes out[b][n] only in the epilogue.
// ---------------------------------------------------------------------------
__global__ __launch_bounds__(512, 2) void k_gemm(
    const float* __restrict__ ie, const __bf16* actA,
    const __bf16* __restrict__ Wt, const float* __restrict__ stats,
    const float* __restrict__ gam, const float* __restrict__ bet,
    const float* __restrict__ bias, float* out) {
  constexpr int BM = 128, BN = 256, BK = 64;
  __shared__ __align__(16) __bf16 As[BM * BK];  // 16 KB
  __shared__ __align__(16) __bf16 Ws[BN * BK];  // 32 KB

  const int n = blockIdx.y;
  const int b0 = blockIdx.x * BM;
  const int t = threadIdx.x;
  const int lane = t & 63;
  const int w = t >> 6;
  const int wm = w & 1;
  const int wn = w >> 1;
  const int l15 = lane & 15;
  const int lq = lane >> 4;
  const int lr8 = lane >> 3;
  const int lo8 = lane & 7;

  const __bf16* Wtn = Wt + (size_t)n * V_DIM * K_DIM;

  // ctx ownership: thread t covers rows pr, pr+64 (pr=t>>3), chunk pm=t&7.
  const int pr = t >> 3;
  const int pm = t & 7;
  // per-row LN stats (two rows per thread)
  const float2 st0 = *(const float2*)(stats + ((size_t)(b0 + pr) * N_F + n) * 2);
  const float2 st1 =
      *(const float2*)(stats + ((size_t)(b0 + pr + 64) * N_F + n) * 2);

  // swizzled ds_write slot (row&7 == pr&7 for both halves)
  const int swo = (pm ^ (pr & 7)) << 3;

  bf16x8 ctx[16];

  f32x4 acc[4][4];
#pragma unroll
  for (int i = 0; i < 4; ++i)
#pragma unroll
    for (int j = 0; j < 4; ++j) acc[i][j] = (f32x4){0.f, 0.f, 0.f, 0.f};

#pragma unroll
  for (int kt = 0; kt < 16; ++kt) {
    const int k0p = (kt ^ 8) * BK;  // physical K offset (0..7 -> masked half)
    __syncthreads();
    // --- stage W tile at permuted K (pre-swizzled global, contiguous gld) ---
#pragma unroll
    for (int p = 0; p < 4; ++p) {
      const int v0 = w * 32 + p * 8;
      gld_lds16(Wtn + (size_t)(v0 + lr8) * K_DIM + k0p + lo8 * 8, Ws + v0 * BK);
    }
    if (kt < 8) {
      // --- A from actA (= d_out alias, pre-swizzled bf16): async copy ---
#pragma unroll
      for (int p = 0; p < 2; ++p) {
        const int r0 = w * 16 + p * 8;
        gld_lds16(actA + ((size_t)(b0 + r0 + lr8) * N_F + n) * H_DIM +
                      (k0p - H_DIM) + lo8 * 8,
                  As + r0 * BK);
      }
      // --- overlapped ctx LN+GELU for step kt+8 (independent of this tile):
      // fills the vmcnt-drain stall with VALU work.
      {
        const int col = kt * 64 + pm * 8;
        const float4 gg0 = *(const float4*)(gam + col);
        const float4 gg1 = *(const float4*)(gam + col + 4);
        const float4 bb0 = *(const float4*)(bet + col);
        const float4 bb1 = *(const float4*)(bet + col + 4);
#pragma unroll
        for (int h = 0; h < 2; ++h) {
          const int row = b0 + pr + 64 * h;
          const float mu = h ? st1.x : st0.x;
          const float rs = h ? st1.y : st0.y;
          const float* ip = ie + (size_t)row * H_DIM + col;
          const float4 x0 = *(const float4*)ip;
          const float4 x1 = *(const float4*)(ip + 4);
          bf16x8 pk;
          pk[0] = (__bf16)gelu_f((x0.x - mu) * rs * gg0.x + bb0.x);
          pk[1] = (__bf16)gelu_f((x0.y - mu) * rs * gg0.y + bb0.y);
          pk[2] = (__bf16)gelu_f((x0.z - mu) * rs * gg0.z + bb0.z);
          pk[3] = (__bf16)gelu_f((x0.w - mu) * rs * gg0.w + bb0.w);
          pk[4] = (__bf16)gelu_f((x1.x - mu) * rs * gg1.x + bb1.x);
          pk[5] = (__bf16)gelu_f((x1.y - mu) * rs * gg1.y + bb1.y);
          pk[6] = (__bf16)gelu_f((x1.z - mu) * rs * gg1.z + bb1.z);
          pk[7] = (__bf16)gelu_f((x1.w - mu) * rs * gg1.w + bb1.w);
          ctx[kt * 2 + h] = pk;
        }
      }
    } else {
      // --- A from ctx regs (computed 8 steps ago): 2 swizzled ds_writes ---
      *(bf16x8*)(As + (pr)*BK + swo) = ctx[(kt - 8) * 2 + 0];
      *(bf16x8*)(As + (pr + 64) * BK + swo) = ctx[(kt - 8) * 2 + 1];
    }
    __syncthreads();
    // --- 2 MFMA k-steps, swizzled fragment reads ---
#pragma unroll
    for (int ks = 0; ks < 2; ++ks) {
      const int cs = ks * 4 + lq;
      bf16x8 af[4], bb[4];
#pragma unroll
      for (int i = 0; i < 4; ++i) {
        const int row = wm * 64 + i * 16 + l15;
        af[i] = *(const bf16x8*)(As + row * BK + ((cs ^ (row & 7)) << 3));
      }
#pragma unroll
      for (int j = 0; j < 4; ++j) {
        const int row = wn * 64 + j * 16 + l15;
        bb[j] = *(const bf16x8*)(Ws + row * BK + ((cs ^ (row & 7)) << 3));
      }
#pragma unroll
      for (int i = 0; i < 4; ++i)
#pragma unroll
        for (int j = 0; j < 4; ++j)
          acc[i][j] = __builtin_amdgcn_mfma_f32_16x16x32_bf16(af[i], bb[j],
                                                              acc[i][j], 0, 0, 0);
    }
  }

  // epilogue: C/D layout col=lane&15, row=(lane>>4)*4+reg
#pragma unroll
  for (int j = 0; j < 4; ++j) {
    const int v = wn * 64 + j * 16 + l15;
    const float bv = bias[n * V_DIM + v];
#pragma unroll
    for (int i = 0; i < 4; ++i) {
      const int rb = wm * 64 + i * 16 + lq * 4;
#pragma unroll
      for (int r = 0; r < 4; ++r) {
        out[((size_t)(b0 + rb + r) * N_F + n) * V_DIM + v] = acc[i][j][r] + bv;
      }
    }
  }
}

// ---------------------------------------------------------------------------
extern "C" void kernel_launch(void* const* d_in, const int* in_sizes, int n_in,
                              void* d_out, int out_size, void* d_ws, size_t ws_size,
                              hipStream_t stream) {
  const float* ie = (const float*)d_in[0];
  const int* feat = (const int*)d_in[1];
  const float* tab = (const float*)d_in[2];
  const float* gam = (const float*)d_in[3];
  const float* bet = (const float*)d_in[4];
  const float* predW = (const float*)d_in[5];
  const float* predb = (const float*)d_in[6];
  float* out = (float*)d_out;

  // activation scratch aliases d_out (exactly out_size bytes)
  __bf16* actA = (__bf16*)d_out;

  char* ws = (char*)d_ws;
  float* stats = (float*)ws;                 //   786,432 B
  __bf16* Wt = (__bf16*)(ws + 786432);       // 6,291,456 B  (ws total ~7 MB)

  hipLaunchKernelGGL(k_prep, dim3(B_SZ / 4), dim3(256), 0, stream, ie, feat,
                     tab, gam, bet, actA, stats);
  hipLaunchKernelGGL(k_wt, dim3(3072), dim3(256), 0, stream, predW, Wt);
  hipLaunchKernelGGL(k_gemm, dim3(B_SZ / 128, N_F), dim3(512), 0, stream, ie,
                     actA, Wt, stats, gam, bet, predb, out);
}

// Round 8
// 268.498 us; speedup vs baseline: 1.1096x; 1.0029x over previous
//
#include <hip/hip_runtime.h>
#include <stdint.h>

#define B_SZ 8192
#define N_F 12
#define H_DIM 512
#define K_DIM 1024
#define V_DIM 256

typedef __attribute__((ext_vector_type(8))) __bf16 bf16x8;
typedef __attribute__((ext_vector_type(4))) float f32x4;

// tanh-approx GELU in sigmoid form; |err| vs exact erf-GELU ~1e-3 << 4.6e-2.
__device__ inline float gelu_f(float x) {
  float t = 1.5957691216057308f * x * (1.0f + 0.044715f * x * x);
  return x / (1.0f + __expf(-t));
}

__device__ inline void gld_lds16(const void* g, void* l) {
  __builtin_amdgcn_global_load_lds(
      (const __attribute__((address_space(1))) void*)g,
      (__attribute__((address_space(3))) void*)l, 16, 0, 0);
}

// ---------------------------------------------------------------------------
// Kernel 1: wave-per-row, masked-sums half only. Lane l owns dims
// [l*8, l*8+8). Activation stored INTO d_out (aliased scratch): layout
// [B][N][H=512] bf16. 16B-chunk XOR swizzle (chunk c at slot c^(b&7)).
// stats[b][n] = (mean, rsqrt).
// ---------------------------------------------------------------------------
__global__ __launch_bounds__(256, 8) void k_prep(
    const float* __restrict__ ie, const int* __restrict__ feat,
    const float* __restrict__ tab, const float* __restrict__ gam,
    const float* __restrict__ bet, __bf16* actA,
    float* __restrict__ stats) {
  const int lane = threadIdx.x & 63;
  const int b = blockIdx.x * 4 + (threadIdx.x >> 6);

  const float* cb = ie + (size_t)b * H_DIM + lane * 8;
  float4 c0 = *(const float4*)cb;
  float4 c1 = *(const float4*)(cb + 4);
  float s = c0.x + c0.y + c0.z + c0.w + c1.x + c1.y + c1.z + c1.w;
  float q = c0.x * c0.x + c0.y * c0.y + c0.z * c0.z + c0.w * c0.w +
            c1.x * c1.x + c1.y * c1.y + c1.z * c1.z + c1.w * c1.w;
#pragma unroll
  for (int o = 1; o < 64; o <<= 1) {
    s += __shfl_xor(s, o, 64);
    q += __shfl_xor(q, o, 64);
  }
  const float S1 = s, Q1 = q;

  const float4 g0 = *(const float4*)(gam + H_DIM + lane * 8);
  const float4 g1 = *(const float4*)(gam + H_DIM + lane * 8 + 4);
  const float4 e0 = *(const float4*)(bet + H_DIM + lane * 8);
  const float4 e1 = *(const float4*)(bet + H_DIM + lane * 8 + 4);

  float r[8];
#pragma unroll
  for (int i = 0; i < 8; ++i) r[i] = 0.f;

  const int sw = (lane & ~7) | ((lane & 7) ^ (b & 7));
  __bf16* arow = actA + (size_t)b * N_F * H_DIM + sw * 8;

  for (int n = 0; n < N_F; ++n) {
    s = 0.f; q = 0.f;
#pragma unroll
    for (int i = 0; i < 8; ++i) { s += r[i]; q += r[i] * r[i]; }
#pragma unroll
    for (int o = 1; o < 64; o <<= 1) {
      s += __shfl_xor(s, o, 64);
      q += __shfl_xor(q, o, 64);
    }
    const float mean = (S1 + s) * (1.0f / 1024.0f);
    const float var = (Q1 + q) * (1.0f / 1024.0f) - mean * mean;
    const float rs = rsqrtf(var + 1e-5f);
    if (lane == 0)
      *(float2*)(stats + ((size_t)b * N_F + n) * 2) = make_float2(mean, rs);

    float4 t0, t1;
    const bool have = (n < N_F - 1);
    if (have) {
      const int f = feat[b * N_F + n];
      const float* tr = tab + ((size_t)n * V_DIM + f) * H_DIM + lane * 8;
      t0 = *(const float4*)tr;
      t1 = *(const float4*)(tr + 4);
    }

    bf16x8 pk;
    pk[0] = (__bf16)gelu_f((r[0] - mean) * rs * g0.x + e0.x);
    pk[1] = (__bf16)gelu_f((r[1] - mean) * rs * g0.y + e0.y);
    pk[2] = (__bf16)gelu_f((r[2] - mean) * rs * g0.z + e0.z);
    pk[3] = (__bf16)gelu_f((r[3] - mean) * rs * g0.w + e0.w);
    pk[4] = (__bf16)gelu_f((r[4] - mean) * rs * g1.x + e1.x);
    pk[5] = (__bf16)gelu_f((r[5] - mean) * rs * g1.y + e1.y);
    pk[6] = (__bf16)gelu_f((r[6] - mean) * rs * g1.z + e1.z);
    pk[7] = (__bf16)gelu_f((r[7] - mean) * rs * g1.w + e1.w);
    *(bf16x8*)(arow + (size_t)n * H_DIM) = pk;

    if (have) {
      r[0] += t0.x; r[1] += t0.y; r[2] += t0.z; r[3] += t0.w;
      r[4] += t1.x; r[5] += t1.y; r[6] += t1.z; r[7] += t1.w;
    }
  }
}

// ---------------------------------------------------------------------------
// Kernel 2: pred_W [N][K][V] fp32 -> Wt [N][V][K] bf16, chunk-swizzled by v&7.
// ---------------------------------------------------------------------------
__global__ __launch_bounds__(256) void k_wt(const float* __restrict__ W,
                                            __bf16* __restrict__ Wt) {
  __shared__ float tile[32][33];
  const int bid = blockIdx.x;
  const int n = bid >> 8;
  const int rem = bid & 255;
  const int kt = rem >> 3, vt = rem & 7;
  const int tx = threadIdx.x & 31, ty = threadIdx.x >> 5;
  const float* src = W + (size_t)n * K_DIM * V_DIM;
#pragma unroll
  for (int i = 0; i < 4; ++i) {
    const int k = kt * 32 + ty + i * 8;
    tile[ty + i * 8][tx] = src[(size_t)k * V_DIM + vt * 32 + tx];
  }
  __syncthreads();
  __bf16* dst = Wt + (size_t)n * V_DIM * K_DIM;
  const int t = threadIdx.x;
  if (t < 128) {
    const int v_l = t >> 2, c_l = t & 3;
    const int v = vt * 32 + v_l;
    bf16x8 pk;
#pragma unroll
    for (int e = 0; e < 8; ++e) pk[e] = (__bf16)tile[c_l * 8 + e][v_l];
    const int gc = kt * 4 + c_l;
    const int swc = (gc & ~7) | ((gc & 7) ^ (v & 7));
    *(bf16x8*)(dst + (size_t)v * K_DIM + swc * 8) = pk;
  }
}

// ---------------------------------------------------------------------------
// Kernel 3: GEMM, 2-barrier loop, masked-first K order (kt^8). ctx half
// (steps 8..15) is fed THROUGH LDS to avoid vmcnt entanglement: ie fp32
// tile c (64 cols) is staged via gld_lds at step c+7 into ieS[c&1] (2x32KB
// ping-pong); consumed at step c+8 as {ds_read -> 16 gelu -> 2 ds_write As}
// — pure lgkm+VALU inside the existing vmcnt-drain shadow. gam/bet staged
// to LDS once in the prologue. Race ledger (all protected by the existing
// 2 syncthreads/step): ieS[c&1] written at step c+7, read at c+8 (RAW via
// barrier); rewritten (tile c+2) at step c+9 > c+8 (WAR via barrier).
// ---------------------------------------------------------------------------
__global__ __launch_bounds__(512, 2) void k_gemm(
    const float* __restrict__ ie, const __bf16* actA,
    const __bf16* __restrict__ Wt, const float* __restrict__ stats,
    const float* __restrict__ gam, const float* __restrict__ bet,
    const float* __restrict__ bias, float* out) {
  constexpr int BM = 128, BN = 256, BK = 64;
  __shared__ __align__(16) __bf16 As[BM * BK];      // 16 KB
  __shared__ __align__(16) __bf16 Ws[BN * BK];      // 32 KB
  __shared__ __align__(16) float ieS[2][BM * BK];   // 64 KB (fp32 ie tiles)
  __shared__ __align__(16) float gamS[H_DIM];       // 2 KB
  __shared__ __align__(16) float betS[H_DIM];       // 2 KB

  const int n = blockIdx.y;
  const int b0 = blockIdx.x * BM;
  const int t = threadIdx.x;
  const int lane = t & 63;
  const int w = t >> 6;
  const int wm = w & 1;
  const int wn = w >> 1;
  const int l15 = lane & 15;
  const int lq = lane >> 4;
  const int lr8 = lane >> 3;
  const int lo8 = lane & 7;

  const __bf16* Wtn = Wt + (size_t)n * V_DIM * K_DIM;

  // --- prologue: stage gam/bet (ctx half, cols 0..511) into LDS ---
  if (w == 0) gld_lds16(gam + lane * 4, gamS + lane * 4);
  else if (w == 1) gld_lds16(gam + 256 + lane * 4, gamS + 256 + lane * 4);
  else if (w == 2) gld_lds16(bet + lane * 4, betS + lane * 4);
  else if (w == 3) gld_lds16(bet + 256 + lane * 4, betS + 256 + lane * 4);

  // ctx ownership: thread t covers rows pr, pr+64 (pr=t>>3), chunk pm=t&7.
  const int pr = t >> 3;
  const int pm = t & 7;
  // per-row LN stats; keep-alive forces the vmcnt wait HERE (prologue),
  // not mid-loop where it would drain the staging queue.
  const float2 st0 = *(const float2*)(stats + ((size_t)(b0 + pr) * N_F + n) * 2);
  const float2 st1 =
      *(const float2*)(stats + ((size_t)(b0 + pr + 64) * N_F + n) * 2);
  asm volatile("" ::"v"(st0.x), "v"(st0.y), "v"(st1.x), "v"(st1.y));

  // swizzled ds_write slot (row&7 == pr&7 for both halves)
  const int swo = (pm ^ (pr & 7)) << 3;

  f32x4 acc[4][4];
#pragma unroll
  for (int i = 0; i < 4; ++i)
#pragma unroll
    for (int j = 0; j < 4; ++j) acc[i][j] = (f32x4){0.f, 0.f, 0.f, 0.f};

#pragma unroll
  for (int kt = 0; kt < 16; ++kt) {
    const int k0p = (kt ^ 8) * BK;  // steps 0..7 -> masked half (cols 512+)
    __syncthreads();
    // --- stage W tile at permuted K (pre-swizzled global -> linear gld) ---
#pragma unroll
    for (int p = 0; p < 4; ++p) {
      const int v0 = w * 32 + p * 8;
      gld_lds16(Wtn + (size_t)(v0 + lr8) * K_DIM + k0p + lo8 * 8, Ws + v0 * BK);
    }
    if (kt < 8) {
      // --- A from actA (= d_out alias, pre-swizzled bf16): async copy ---
#pragma unroll
      for (int p = 0; p < 2; ++p) {
        const int r0 = w * 16 + p * 8;
        gld_lds16(actA + ((size_t)(b0 + r0 + lr8) * N_F + n) * H_DIM +
                      (k0p - H_DIM) + lo8 * 8,
                  As + r0 * BK);
      }
    } else {
      // --- ctx from ieS (staged last step): ds_read -> gelu -> ds_write.
      // Pure LDS+VALU: no vmcnt touch, staging glds stay in flight.
      const int c = kt - 8;
      const int col = c * 64 + pm * 8;
      const float4 gg0 = *(const float4*)(gamS + col);
      const float4 gg1 = *(const float4*)(gamS + col + 4);
      const float4 bb0 = *(const float4*)(betS + col);
      const float4 bb1 = *(const float4*)(betS + col + 4);
      const float* tile = ieS[c & 1];
      {
        const float4 x0 = *(const float4*)(tile + pr * 64 + pm * 8);
        const float4 x1 = *(const float4*)(tile + pr * 64 + pm * 8 + 4);
        const float mu = st0.x, rs = st0.y;
        bf16x8 pk;
        pk[0] = (__bf16)gelu_f((x0.x - mu) * rs * gg0.x + bb0.x);
        pk[1] = (__bf16)gelu_f((x0.y - mu) * rs * gg0.y + bb0.y);
        pk[2] = (__bf16)gelu_f((x0.z - mu) * rs * gg0.z + bb0.z);
        pk[3] = (__bf16)gelu_f((x0.w - mu) * rs * gg0.w + bb0.w);
        pk[4] = (__bf16)gelu_f((x1.x - mu) * rs * gg1.x + bb1.x);
        pk[5] = (__bf16)gelu_f((x1.y - mu) * rs * gg1.y + bb1.y);
        pk[6] = (__bf16)gelu_f((x1.z - mu) * rs * gg1.z + bb1.z);
        pk[7] = (__bf16)gelu_f((x1.w - mu) * rs * gg1.w + bb1.w);
        *(bf16x8*)(As + pr * BK + swo) = pk;
      }
      {
        const float4 x0 = *(const float4*)(tile + (pr + 64) * 64 + pm * 8);
        const float4 x1 = *(const float4*)(tile + (pr + 64) * 64 + pm * 8 + 4);
        const float mu = st1.x, rs = st1.y;
        bf16x8 pk;
        pk[0] = (__bf16)gelu_f((x0.x - mu) * rs * gg0.x + bb0.x);
        pk[1] = (__bf16)gelu_f((x0.y - mu) * rs * gg0.y + bb0.y);
        pk[2] = (__bf16)gelu_f((x0.z - mu) * rs * gg0.z + bb0.z);
        pk[3] = (__bf16)gelu_f((x0.w - mu) * rs * gg0.w + bb0.w);
        pk[4] = (__bf16)gelu_f((x1.x - mu) * rs * gg1.x + bb1.x);
        pk[5] = (__bf16)gelu_f((x1.y - mu) * rs * gg1.y + bb1.y);
        pk[6] = (__bf16)gelu_f((x1.z - mu) * rs * gg1.z + bb1.z);
        pk[7] = (__bf16)gelu_f((x1.w - mu) * rs * gg1.w + bb1.w);
        *(bf16x8*)(As + (pr + 64) * BK + swo) = pk;
      }
    }
    // --- stage ie fp32 tile (kt-7) for next step's ctx, linear gld ---
    if (kt >= 7 && kt < 15) {
      const int c = kt - 7;
      float* dst = ieS[c & 1];
#pragma unroll
      for (int i = 0; i < 4; ++i) {
        const int c4 = i * 512 + t;  // 16B chunk index, 2048 total
        gld_lds16(ie + (size_t)(b0 + (c4 >> 4)) * H_DIM + c * 64 + (c4 & 15) * 4,
                  dst + c4 * 4);
      }
    }
    __syncthreads();
    // --- 2 MFMA k-steps, swizzled fragment reads ---
#pragma unroll
    for (int ks = 0; ks < 2; ++ks) {
      const int cs = ks * 4 + lq;
      bf16x8 af[4], bb[4];
#pragma unroll
      for (int i = 0; i < 4; ++i) {
        const int row = wm * 64 + i * 16 + l15;
        af[i] = *(const bf16x8*)(As + row * BK + ((cs ^ (row & 7)) << 3));
      }
#pragma unroll
      for (int j = 0; j < 4; ++j) {
        const int row = wn * 64 + j * 16 + l15;
        bb[j] = *(const bf16x8*)(Ws + row * BK + ((cs ^ (row & 7)) << 3));
      }
#pragma unroll
      for (int i = 0; i < 4; ++i)
#pragma unroll
        for (int j = 0; j < 4; ++j)
          acc[i][j] = __builtin_amdgcn_mfma_f32_16x16x32_bf16(af[i], bb[j],
                                                              acc[i][j], 0, 0, 0);
    }
  }

  // epilogue: C/D layout col=lane&15, row=(lane>>4)*4+reg
#pragma unroll
  for (int j = 0; j < 4; ++j) {
    const int v = wn * 64 + j * 16 + l15;
    const float bv = bias[n * V_DIM + v];
#pragma unroll
    for (int i = 0; i < 4; ++i) {
      const int rb = wm * 64 + i * 16 + lq * 4;
#pragma unroll
      for (int r = 0; r < 4; ++r) {
        out[((size_t)(b0 + rb + r) * N_F + n) * V_DIM + v] = acc[i][j][r] + bv;
      }
    }
  }
}

// ---------------------------------------------------------------------------
extern "C" void kernel_launch(void* const* d_in, const int* in_sizes, int n_in,
                              void* d_out, int out_size, void* d_ws, size_t ws_size,
                              hipStream_t stream) {
  const float* ie = (const float*)d_in[0];
  const int* feat = (const int*)d_in[1];
  const float* tab = (const float*)d_in[2];
  const float* gam = (const float*)d_in[3];
  const float* bet = (const float*)d_in[4];
  const float* predW = (const float*)d_in[5];
  const float* predb = (const float*)d_in[6];
  float* out = (float*)d_out;

  // activation scratch aliases d_out (exactly out_size bytes)
  __bf16* actA = (__bf16*)d_out;

  char* ws = (char*)d_ws;
  float* stats = (float*)ws;                 //   786,432 B
  __bf16* Wt = (__bf16*)(ws + 786432);       // 6,291,456 B  (ws total ~7 MB)

  hipLaunchKernelGGL(k_prep, dim3(B_SZ / 4), dim3(256), 0, stream, ie, feat,
                     tab, gam, bet, actA, stats);
  hipLaunchKernelGGL(k_wt, dim3(3072), dim3(256), 0, stream, predW, Wt);
  hipLaunchKernelGGL(k_gemm, dim3(B_SZ / 128, N_F), dim3(512), 0, stream, ie,
                     actA, Wt, stats, gam, bet, predb, out);
}

// Round 9
// 262.302 us; speedup vs baseline: 1.1359x; 1.0236x over previous
//
#include <hip/hip_runtime.h>
#include <stdint.h>

#define B_SZ 8192
#define N_F 12
#define H_DIM 512
#define K_DIM 1024
#define V_DIM 256

typedef __attribute__((ext_vector_type(8))) __bf16 bf16x8;
typedef __attribute__((ext_vector_type(4))) float f32x4;

// tanh-approx GELU in sigmoid form; |err| vs exact erf-GELU ~1e-3 << 4.6e-2.
__device__ inline float gelu_f(float x) {
  float t = 1.5957691216057308f * x * (1.0f + 0.044715f * x * x);
  return x / (1.0f + __expf(-t));
}

__device__ inline void gld_lds16(const void* g, void* l) {
  __builtin_amdgcn_global_load_lds(
      (const __attribute__((address_space(1))) void*)g,
      (__attribute__((address_space(3))) void*)l, 16, 0, 0);
}

// ---------------------------------------------------------------------------
// Kernel 1: wave-per-row. Lane l owns dims [l*8, l*8+8) of H=512.
// Emits BOTH activation halves per n, pre-swizzled (chunk c at slot c^(b&7)
// within each 64-elem K-group):
//   masked-sums half -> actA  = d_out alias, [B][N][512] bf16
//   ctx half         -> ctx2  = ws,          [B][N][512] bf16
// k_gemm is then a PURE GEMM (no stats / gam / bet needed downstream).
// ---------------------------------------------------------------------------
__global__ __launch_bounds__(256, 4) void k_prep(
    const float* __restrict__ ie, const int* __restrict__ feat,
    const float* __restrict__ tab, const float* __restrict__ gam,
    const float* __restrict__ bet, __bf16* actA, __bf16* __restrict__ ctx2) {
  const int lane = threadIdx.x & 63;
  const int b = blockIdx.x * 4 + (threadIdx.x >> 6);

  const float* cb = ie + (size_t)b * H_DIM + lane * 8;
  float4 c0 = *(const float4*)cb;
  float4 c1 = *(const float4*)(cb + 4);
  float s = c0.x + c0.y + c0.z + c0.w + c1.x + c1.y + c1.z + c1.w;
  float q = c0.x * c0.x + c0.y * c0.y + c0.z * c0.z + c0.w * c0.w +
            c1.x * c1.x + c1.y * c1.y + c1.z * c1.z + c1.w * c1.w;
#pragma unroll
  for (int o = 1; o < 64; o <<= 1) {
    s += __shfl_xor(s, o, 64);
    q += __shfl_xor(q, o, 64);
  }
  const float S1 = s, Q1 = q;

  const float4 gl0 = *(const float4*)(gam + lane * 8);
  const float4 gl1 = *(const float4*)(gam + lane * 8 + 4);
  const float4 el0 = *(const float4*)(bet + lane * 8);
  const float4 el1 = *(const float4*)(bet + lane * 8 + 4);
  const float4 g0 = *(const float4*)(gam + H_DIM + lane * 8);
  const float4 g1 = *(const float4*)(gam + H_DIM + lane * 8 + 4);
  const float4 e0 = *(const float4*)(bet + H_DIM + lane * 8);
  const float4 e1 = *(const float4*)(bet + H_DIM + lane * 8 + 4);

  float r[8];
#pragma unroll
  for (int i = 0; i < 8; ++i) r[i] = 0.f;

  const int sw = (lane & ~7) | ((lane & 7) ^ (b & 7));
  __bf16* arowM = actA + (size_t)b * N_F * H_DIM + sw * 8;
  __bf16* arowC = ctx2 + (size_t)b * N_F * H_DIM + sw * 8;

  for (int n = 0; n < N_F; ++n) {
    s = 0.f; q = 0.f;
#pragma unroll
    for (int i = 0; i < 8; ++i) { s += r[i]; q += r[i] * r[i]; }
#pragma unroll
    for (int o = 1; o < 64; o <<= 1) {
      s += __shfl_xor(s, o, 64);
      q += __shfl_xor(q, o, 64);
    }
    const float mean = (S1 + s) * (1.0f / 1024.0f);
    const float var = (Q1 + q) * (1.0f / 1024.0f) - mean * mean;
    const float rs = rsqrtf(var + 1e-5f);

    // issue next gather early so latency hides under the gelu work
    float4 t0, t1;
    const bool have = (n < N_F - 1);
    if (have) {
      const int f = feat[b * N_F + n];
      const float* tr = tab + ((size_t)n * V_DIM + f) * H_DIM + lane * 8;
      t0 = *(const float4*)tr;
      t1 = *(const float4*)(tr + 4);
    }

    // ctx half (k in [0,512)) -> ctx2
    bf16x8 pc;
    pc[0] = (__bf16)gelu_f((c0.x - mean) * rs * gl0.x + el0.x);
    pc[1] = (__bf16)gelu_f((c0.y - mean) * rs * gl0.y + el0.y);
    pc[2] = (__bf16)gelu_f((c0.z - mean) * rs * gl0.z + el0.z);
    pc[3] = (__bf16)gelu_f((c0.w - mean) * rs * gl0.w + el0.w);
    pc[4] = (__bf16)gelu_f((c1.x - mean) * rs * gl1.x + el1.x);
    pc[5] = (__bf16)gelu_f((c1.y - mean) * rs * gl1.y + el1.y);
    pc[6] = (__bf16)gelu_f((c1.z - mean) * rs * gl1.z + el1.z);
    pc[7] = (__bf16)gelu_f((c1.w - mean) * rs * gl1.w + el1.w);
    *(bf16x8*)(arowC + (size_t)n * H_DIM) = pc;

    // masked-sums half (k in [512,1024)) -> actA (= d_out alias)
    bf16x8 pk;
    pk[0] = (__bf16)gelu_f((r[0] - mean) * rs * g0.x + e0.x);
    pk[1] = (__bf16)gelu_f((r[1] - mean) * rs * g0.y + e0.y);
    pk[2] = (__bf16)gelu_f((r[2] - mean) * rs * g0.z + e0.z);
    pk[3] = (__bf16)gelu_f((r[3] - mean) * rs * g0.w + e0.w);
    pk[4] = (__bf16)gelu_f((r[4] - mean) * rs * g1.x + e1.x);
    pk[5] = (__bf16)gelu_f((r[5] - mean) * rs * g1.y + e1.y);
    pk[6] = (__bf16)gelu_f((r[6] - mean) * rs * g1.z + e1.z);
    pk[7] = (__bf16)gelu_f((r[7] - mean) * rs * g1.w + e1.w);
    *(bf16x8*)(arowM + (size_t)n * H_DIM) = pk;

    if (have) {
      r[0] += t0.x; r[1] += t0.y; r[2] += t0.z; r[3] += t0.w;
      r[4] += t1.x; r[5] += t1.y; r[6] += t1.z; r[7] += t1.w;
    }
  }
}

// ---------------------------------------------------------------------------
// Kernel 2: pred_W [N][K][V] fp32 -> Wt [N][V][K] bf16, chunk-swizzled by v&7.
// ---------------------------------------------------------------------------
__global__ __launch_bounds__(256) void k_wt(const float* __restrict__ W,
                                            __bf16* __restrict__ Wt) {
  __shared__ float tile[32][33];
  const int bid = blockIdx.x;
  const int n = bid >> 8;
  const int rem = bid & 255;
  const int kt = rem >> 3, vt = rem & 7;
  const int tx = threadIdx.x & 31, ty = threadIdx.x >> 5;
  const float* src = W + (size_t)n * K_DIM * V_DIM;
#pragma unroll
  for (int i = 0; i < 4; ++i) {
    const int k = kt * 32 + ty + i * 8;
    tile[ty + i * 8][tx] = src[(size_t)k * V_DIM + vt * 32 + tx];
  }
  __syncthreads();
  __bf16* dst = Wt + (size_t)n * V_DIM * K_DIM;
  const int t = threadIdx.x;
  if (t < 128) {
    const int v_l = t >> 2, c_l = t & 3;
    const int v = vt * 32 + v_l;
    bf16x8 pk;
#pragma unroll
    for (int e = 0; e < 8; ++e) pk[e] = (__bf16)tile[c_l * 8 + e][v_l];
    const int gc = kt * 4 + c_l;
    const int swc = (gc & ~7) | ((gc & 7) ^ (v & 7));
    *(bf16x8*)(dst + (size_t)v * K_DIM + swc * 8) = pk;
  }
}

// ---------------------------------------------------------------------------
// Kernel 3: PURE GEMM, occupancy-first geometry. grid = (B/64, N), 256
// threads (4 waves, 1x4). BM=64 BN=256 BK=64. LDS = As 8KB + Ws 32KB = 40KB.
// Low regs (acc 4x4 = 64 AGPR) + __launch_bounds__(256,3) target >=3
// blocks/CU so cross-block TLP hides the per-block barrier drain (m114
// mechanism) instead of in-block scheduling. Same proven 2-barrier loop,
// swizzled LDS, gld_lds staging. K order: kt<8 -> ctx2, kt>=8 -> actA.
// Alias: actA aliases d_out; block (b-block, n) exclusively owns its
// act/out cells (BN=256 = full V) -> reads (kt>=8) precede epilogue writes
// within the same block only. No cross-block hazard.
// ---------------------------------------------------------------------------
__global__ __launch_bounds__(256, 3) void k_gemm(
    const __bf16* __restrict__ ctx2, const __bf16* actA,
    const __bf16* __restrict__ Wt, const float* __restrict__ bias,
    float* out) {
  constexpr int BM = 64, BN = 256, BK = 64;
  __shared__ __align__(16) __bf16 As[BM * BK];  // 8 KB
  __shared__ __align__(16) __bf16 Ws[BN * BK];  // 32 KB

  const int n = blockIdx.y;
  const int b0 = blockIdx.x * BM;
  const int t = threadIdx.x;
  const int lane = t & 63;
  const int w = t >> 6;  // 0..3, owns v block w*64
  const int l15 = lane & 15;
  const int lq = lane >> 4;
  const int lr8 = lane >> 3;
  const int lo8 = lane & 7;

  const __bf16* Wtn = Wt + (size_t)n * V_DIM * K_DIM;

  f32x4 acc[4][4];
#pragma unroll
  for (int i = 0; i < 4; ++i)
#pragma unroll
    for (int j = 0; j < 4; ++j) acc[i][j] = (f32x4){0.f, 0.f, 0.f, 0.f};

#pragma unroll
  for (int kt = 0; kt < 16; ++kt) {
    __syncthreads();
    // --- stage W tile: 4 glds/wave (wave w covers v rows w*64..w*64+63
    //     via v0 = w*64 + p*16? no: rows w*64+p*... use p<8 rows-of-8) ---
#pragma unroll
    for (int p = 0; p < 4; ++p) {
      const int v0 = w * 64 + p * 16 + (lr8 & 8);  // two 8-row groups per p
      // simpler: rows w*64 + p*16 + (lr8>=8?8:0)... keep canonical form:
      (void)v0;
    }
    // canonical staging: 64 rows per wave, 8 rows per gld
#pragma unroll
    for (int p = 0; p < 8; p += 2) {
      const int r0 = w * 64 + p * 8;
      gld_lds16(Wtn + (size_t)(r0 + lr8) * K_DIM + kt * BK + lo8 * 8,
                Ws + r0 * BK);
      const int r1 = w * 64 + (p + 1) * 8;
      gld_lds16(Wtn + (size_t)(r1 + lr8) * K_DIM + kt * BK + lo8 * 8,
                Ws + r1 * BK);
    }
    // --- stage A tile: 2 glds/wave (64 rows total, 16 rows per wave) ---
    {
      const __bf16* src = (kt < 8) ? ctx2 : actA;
      const int kc = (kt < 8) ? kt * 64 : (kt - 8) * 64;
#pragma unroll
      for (int p = 0; p < 2; ++p) {
        const int r0 = w * 16 + p * 8;
        gld_lds16(src + ((size_t)(b0 + r0 + lr8) * N_F + n) * H_DIM + kc +
                      lo8 * 8,
                  As + r0 * BK);
      }
    }
    __syncthreads();
    // --- 2 MFMA k-steps, swizzled fragment reads ---
#pragma unroll
    for (int ks = 0; ks < 2; ++ks) {
      const int cs = ks * 4 + lq;
      bf16x8 af[4], bb[4];
#pragma unroll
      for (int i = 0; i < 4; ++i) {
        const int row = i * 16 + l15;  // A rows 0..63
        af[i] = *(const bf16x8*)(As + row * BK + ((cs ^ (row & 7)) << 3));
      }
#pragma unroll
      for (int j = 0; j < 4; ++j) {
        const int row = w * 64 + j * 16 + l15;  // V rows, wave-owned block
        bb[j] = *(const bf16x8*)(Ws + row * BK + ((cs ^ (row & 7)) << 3));
      }
#pragma unroll
      for (int i = 0; i < 4; ++i)
#pragma unroll
        for (int j = 0; j < 4; ++j)
          acc[i][j] = __builtin_amdgcn_mfma_f32_16x16x32_bf16(af[i], bb[j],
                                                              acc[i][j], 0, 0, 0);
    }
  }

  // epilogue: C/D layout col=lane&15, row=(lane>>4)*4+reg
#pragma unroll
  for (int j = 0; j < 4; ++j) {
    const int v = w * 64 + j * 16 + l15;
    const float bv = bias[n * V_DIM + v];
#pragma unroll
    for (int i = 0; i < 4; ++i) {
      const int rb = i * 16 + lq * 4;
#pragma unroll
      for (int r = 0; r < 4; ++r) {
        out[((size_t)(b0 + rb + r) * N_F + n) * V_DIM + v] = acc[i][j][r] + bv;
      }
    }
  }
}

// ---------------------------------------------------------------------------
extern "C" void kernel_launch(void* const* d_in, const int* in_sizes, int n_in,
                              void* d_out, int out_size, void* d_ws, size_t ws_size,
                              hipStream_t stream) {
  const float* ie = (const float*)d_in[0];
  const int* feat = (const int*)d_in[1];
  const float* tab = (const float*)d_in[2];
  const float* gam = (const float*)d_in[3];
  const float* bet = (const float*)d_in[4];
  const float* predW = (const float*)d_in[5];
  const float* predb = (const float*)d_in[6];
  float* out = (float*)d_out;

  // masked-half activation aliases d_out (exactly out_size bytes)
  __bf16* actA = (__bf16*)d_out;

  char* ws = (char*)d_ws;
  __bf16* ctx2 = (__bf16*)ws;                        // 100,663,296 B
  __bf16* Wt = (__bf16*)(ws + 100663296);            //   6,291,456 B

  hipLaunchKernelGGL(k_prep, dim3(B_SZ / 4), dim3(256), 0, stream, ie, feat,
                     tab, gam, bet, actA, ctx2);
  hipLaunchKernelGGL(k_wt, dim3(3072), dim3(256), 0, stream, predW, Wt);
  hipLaunchKernelGGL(k_gemm, dim3(B_SZ / 64, N_F), dim3(256), 0, stream,
                     ctx2, actA, Wt, predb, out);
}

// Round 10
// 239.621 us; speedup vs baseline: 1.2434x; 1.0947x over previous
//
#include <hip/hip_runtime.h>
#include <stdint.h>

#define B_SZ 8192
#define N_F 12
#define H_DIM 512
#define K_DIM 1024
#define V_DIM 256

typedef __attribute__((ext_vector_type(8))) __bf16 bf16x8;
typedef __attribute__((ext_vector_type(4))) float f32x4;

// tanh-approx GELU, sigmoid form, DIVISION-FREE (v_rcp instead of IEEE div;
// ~1 ulp rcp error is noise vs the 1e-3 approx error; absmax margin ~3x).
// t = 1.5957691*x*(1+0.044715*x^2)  ->  -t = x*(-1.5957691 - 0.07135481*x^2)
__device__ inline float gelu_f(float x) {
  const float u = x * x;
  const float nt = x * fmaf(-0.071354814f, u, -1.5957691216f);
  return x * __builtin_amdgcn_rcpf(1.0f + __expf(nt));
}

__device__ inline void gld_lds16(const void* g, void* l) {
  __builtin_amdgcn_global_load_lds(
      (const __attribute__((address_space(1))) void*)g,
      (__attribute__((address_space(3))) void*)l, 16, 0, 0);
}

// ---------------------------------------------------------------------------
// Kernel 1: wave-per-row. Lane l owns dims [l*8, l*8+8) of H=512.
// Emits BOTH activation halves per n, pre-swizzled (chunk c at slot c^(b&7)
// within each 64-elem K-group):
//   masked-sums half -> actA  = d_out alias, [B][N][512] bf16
//   ctx half         -> ctx2  = ws,          [B][N][512] bf16
// k_gemm is then a PURE GEMM.
// ---------------------------------------------------------------------------
__global__ __launch_bounds__(256, 4) void k_prep(
    const float* __restrict__ ie, const int* __restrict__ feat,
    const float* __restrict__ tab, const float* __restrict__ gam,
    const float* __restrict__ bet, __bf16* actA, __bf16* __restrict__ ctx2) {
  const int lane = threadIdx.x & 63;
  const int b = blockIdx.x * 4 + (threadIdx.x >> 6);

  const float* cb = ie + (size_t)b * H_DIM + lane * 8;
  float4 c0 = *(const float4*)cb;
  float4 c1 = *(const float4*)(cb + 4);
  float s = c0.x + c0.y + c0.z + c0.w + c1.x + c1.y + c1.z + c1.w;
  float q = c0.x * c0.x + c0.y * c0.y + c0.z * c0.z + c0.w * c0.w +
            c1.x * c1.x + c1.y * c1.y + c1.z * c1.z + c1.w * c1.w;
#pragma unroll
  for (int o = 1; o < 64; o <<= 1) {
    s += __shfl_xor(s, o, 64);
    q += __shfl_xor(q, o, 64);
  }
  const float S1 = s, Q1 = q;

  const float4 gl0 = *(const float4*)(gam + lane * 8);
  const float4 gl1 = *(const float4*)(gam + lane * 8 + 4);
  const float4 el0 = *(const float4*)(bet + lane * 8);
  const float4 el1 = *(const float4*)(bet + lane * 8 + 4);
  const float4 g0 = *(const float4*)(gam + H_DIM + lane * 8);
  const float4 g1 = *(const float4*)(gam + H_DIM + lane * 8 + 4);
  const float4 e0 = *(const float4*)(bet + H_DIM + lane * 8);
  const float4 e1 = *(const float4*)(bet + H_DIM + lane * 8 + 4);

  float r[8];
#pragma unroll
  for (int i = 0; i < 8; ++i) r[i] = 0.f;

  const int sw = (lane & ~7) | ((lane & 7) ^ (b & 7));
  __bf16* arowM = actA + (size_t)b * N_F * H_DIM + sw * 8;
  __bf16* arowC = ctx2 + (size_t)b * N_F * H_DIM + sw * 8;

  for (int n = 0; n < N_F; ++n) {
    s = 0.f; q = 0.f;
#pragma unroll
    for (int i = 0; i < 8; ++i) { s += r[i]; q += r[i] * r[i]; }
#pragma unroll
    for (int o = 1; o < 64; o <<= 1) {
      s += __shfl_xor(s, o, 64);
      q += __shfl_xor(q, o, 64);
    }
    const float mean = (S1 + s) * (1.0f / 1024.0f);
    const float var = (Q1 + q) * (1.0f / 1024.0f) - mean * mean;
    const float rs = __builtin_amdgcn_rsqf(var + 1e-5f);

    // issue next gather early so latency hides under the gelu work
    float4 t0, t1;
    const bool have = (n < N_F - 1);
    if (have) {
      const int f = feat[b * N_F + n];
      const float* tr = tab + ((size_t)n * V_DIM + f) * H_DIM + lane * 8;
      t0 = *(const float4*)tr;
      t1 = *(const float4*)(tr + 4);
    }

    // ctx half (k in [0,512)) -> ctx2
    bf16x8 pc;
    pc[0] = (__bf16)gelu_f((c0.x - mean) * rs * gl0.x + el0.x);
    pc[1] = (__bf16)gelu_f((c0.y - mean) * rs * gl0.y + el0.y);
    pc[2] = (__bf16)gelu_f((c0.z - mean) * rs * gl0.z + el0.z);
    pc[3] = (__bf16)gelu_f((c0.w - mean) * rs * gl0.w + el0.w);
    pc[4] = (__bf16)gelu_f((c1.x - mean) * rs * gl1.x + el1.x);
    pc[5] = (__bf16)gelu_f((c1.y - mean) * rs * gl1.y + el1.y);
    pc[6] = (__bf16)gelu_f((c1.z - mean) * rs * gl1.z + el1.z);
    pc[7] = (__bf16)gelu_f((c1.w - mean) * rs * gl1.w + el1.w);
    *(bf16x8*)(arowC + (size_t)n * H_DIM) = pc;

    // masked-sums half (k in [512,1024)) -> actA (= d_out alias)
    bf16x8 pk;
    pk[0] = (__bf16)gelu_f((r[0] - mean) * rs * g0.x + e0.x);
    pk[1] = (__bf16)gelu_f((r[1] - mean) * rs * g0.y + e0.y);
    pk[2] = (__bf16)gelu_f((r[2] - mean) * rs * g0.z + e0.z);
    pk[3] = (__bf16)gelu_f((r[3] - mean) * rs * g0.w + e0.w);
    pk[4] = (__bf16)gelu_f((r[4] - mean) * rs * g1.x + e1.x);
    pk[5] = (__bf16)gelu_f((r[5] - mean) * rs * g1.y + e1.y);
    pk[6] = (__bf16)gelu_f((r[6] - mean) * rs * g1.z + e1.z);
    pk[7] = (__bf16)gelu_f((r[7] - mean) * rs * g1.w + e1.w);
    *(bf16x8*)(arowM + (size_t)n * H_DIM) = pk;

    if (have) {
      r[0] += t0.x; r[1] += t0.y; r[2] += t0.z; r[3] += t0.w;
      r[4] += t1.x; r[5] += t1.y; r[6] += t1.z; r[7] += t1.w;
    }
  }
}

// ---------------------------------------------------------------------------
// Kernel 2: pred_W [N][K][V] fp32 -> Wt [N][V][K] bf16, chunk-swizzled by v&7.
// ---------------------------------------------------------------------------
__global__ __launch_bounds__(256) void k_wt(const float* __restrict__ W,
                                            __bf16* __restrict__ Wt) {
  __shared__ float tile[32][33];
  const int bid = blockIdx.x;
  const int n = bid >> 8;
  const int rem = bid & 255;
  const int kt = rem >> 3, vt = rem & 7;
  const int tx = threadIdx.x & 31, ty = threadIdx.x >> 5;
  const float* src = W + (size_t)n * K_DIM * V_DIM;
#pragma unroll
  for (int i = 0; i < 4; ++i) {
    const int k = kt * 32 + ty + i * 8;
    tile[ty + i * 8][tx] = src[(size_t)k * V_DIM + vt * 32 + tx];
  }
  __syncthreads();
  __bf16* dst = Wt + (size_t)n * V_DIM * K_DIM;
  const int t = threadIdx.x;
  if (t < 128) {
    const int v_l = t >> 2, c_l = t & 3;
    const int v = vt * 32 + v_l;
    bf16x8 pk;
#pragma unroll
    for (int e = 0; e < 8; ++e) pk[e] = (__bf16)tile[c_l * 8 + e][v_l];
    const int gc = kt * 4 + c_l;
    const int swc = (gc & ~7) | ((gc & 7) ^ (v & 7));
    *(bf16x8*)(dst + (size_t)v * K_DIM + swc * 8) = pk;
  }
}

// ---------------------------------------------------------------------------
// Kernel 3: PURE GEMM, occupancy-first geometry (R9-verified). grid =
// (B/64, N), 256 threads (4 waves, 1x4). BM=64 BN=256 BK=64. LDS 40 KB,
// low regs, __launch_bounds__(256,3): >=3 blocks/CU so cross-block TLP
// hides the barrier drain (m114). 2-barrier loop, swizzled LDS, gld_lds
// staging. K order: kt<8 -> ctx2, kt>=8 -> actA.
// Alias: actA aliases d_out; block (b-block, n) exclusively owns its
// act/out cells (BN=256 = full V); reads precede epilogue writes in-block.
// ---------------------------------------------------------------------------
__global__ __launch_bounds__(256, 3) void k_gemm(
    const __bf16* __restrict__ ctx2, const __bf16* actA,
    const __bf16* __restrict__ Wt, const float* __restrict__ bias,
    float* out) {
  constexpr int BM = 64, BN = 256, BK = 64;
  __shared__ __align__(16) __bf16 As[BM * BK];  // 8 KB
  __shared__ __align__(16) __bf16 Ws[BN * BK];  // 32 KB

  const int n = blockIdx.y;
  const int b0 = blockIdx.x * BM;
  const int t = threadIdx.x;
  const int lane = t & 63;
  const int w = t >> 6;  // 0..3, owns v block w*64
  const int l15 = lane & 15;
  const int lq = lane >> 4;
  const int lr8 = lane >> 3;
  const int lo8 = lane & 7;

  const __bf16* Wtn = Wt + (size_t)n * V_DIM * K_DIM;

  f32x4 acc[4][4];
#pragma unroll
  for (int i = 0; i < 4; ++i)
#pragma unroll
    for (int j = 0; j < 4; ++j) acc[i][j] = (f32x4){0.f, 0.f, 0.f, 0.f};

#pragma unroll
  for (int kt = 0; kt < 16; ++kt) {
    __syncthreads();
    // --- stage W tile: 8 glds/wave (wave w owns v rows w*64..w*64+63) ---
#pragma unroll
    for (int p = 0; p < 8; ++p) {
      const int r0 = w * 64 + p * 8;
      gld_lds16(Wtn + (size_t)(r0 + lr8) * K_DIM + kt * BK + lo8 * 8,
                Ws + r0 * BK);
    }
    // --- stage A tile: 2 glds/wave (64 rows total, 16 rows per wave) ---
    {
      const __bf16* src = (kt < 8) ? ctx2 : actA;
      const int kc = (kt < 8) ? kt * 64 : (kt - 8) * 64;
#pragma unroll
      for (int p = 0; p < 2; ++p) {
        const int r0 = w * 16 + p * 8;
        gld_lds16(src + ((size_t)(b0 + r0 + lr8) * N_F + n) * H_DIM + kc +
                      lo8 * 8,
                  As + r0 * BK);
      }
    }
    __syncthreads();
    // --- 2 MFMA k-steps, swizzled fragment reads ---
#pragma unroll
    for (int ks = 0; ks < 2; ++ks) {
      const int cs = ks * 4 + lq;
      bf16x8 af[4], bb[4];
#pragma unroll
      for (int i = 0; i < 4; ++i) {
        const int row = i * 16 + l15;  // A rows 0..63
        af[i] = *(const bf16x8*)(As + row * BK + ((cs ^ (row & 7)) << 3));
      }
#pragma unroll
      for (int j = 0; j < 4; ++j) {
        const int row = w * 64 + j * 16 + l15;  // V rows, wave-owned block
        bb[j] = *(const bf16x8*)(Ws + row * BK + ((cs ^ (row & 7)) << 3));
      }
#pragma unroll
      for (int i = 0; i < 4; ++i)
#pragma unroll
        for (int j = 0; j < 4; ++j)
          acc[i][j] = __builtin_amdgcn_mfma_f32_16x16x32_bf16(af[i], bb[j],
                                                              acc[i][j], 0, 0, 0);
    }
  }

  // epilogue: C/D layout col=lane&15, row=(lane>>4)*4+reg
#pragma unroll
  for (int j = 0; j < 4; ++j) {
    const int v = w * 64 + j * 16 + l15;
    const float bv = bias[n * V_DIM + v];
#pragma unroll
    for (int i = 0; i < 4; ++i) {
      const int rb = i * 16 + lq * 4;
#pragma unroll
      for (int r = 0; r < 4; ++r) {
        out[((size_t)(b0 + rb + r) * N_F + n) * V_DIM + v] = acc[i][j][r] + bv;
      }
    }
  }
}

// ---------------------------------------------------------------------------
extern "C" void kernel_launch(void* const* d_in, const int* in_sizes, int n_in,
                              void* d_out, int out_size, void* d_ws, size_t ws_size,
                              hipStream_t stream) {
  const float* ie = (const float*)d_in[0];
  const int* feat = (const int*)d_in[1];
  const float* tab = (const float*)d_in[2];
  const float* gam = (const float*)d_in[3];
  const float* bet = (const float*)d_in[4];
  const float* predW = (const float*)d_in[5];
  const float* predb = (const float*)d_in[6];
  float* out = (float*)d_out;

  // masked-half activation aliases d_out (exactly out_size bytes)
  __bf16* actA = (__bf16*)d_out;

  char* ws = (char*)d_ws;
  __bf16* ctx2 = (__bf16*)ws;                        // 100,663,296 B
  __bf16* Wt = (__bf16*)(ws + 100663296);            //   6,291,456 B

  hipLaunchKernelGGL(k_prep, dim3(B_SZ / 4), dim3(256), 0, stream, ie, feat,
                     tab, gam, bet, actA, ctx2);
  hipLaunchKernelGGL(k_wt, dim3(3072), dim3(256), 0, stream, predW, Wt);
  hipLaunchKernelGGL(k_gemm, dim3(B_SZ / 64, N_F), dim3(256), 0, stream,
                     ctx2, actA, Wt, predb, out);
}